// Round 1
// baseline (245.219 us; speedup 1.0000x reference)
//
#include <hip/hip_runtime.h>
#include <hip/hip_bf16.h>
#include <math.h>

// Problem: N=50000 nodes, E=800000 edges, D=G=128.
// out[v,:] = elu( sum_{e: dst(e)=v} softmax_e(leaky(pd[dst]+ps[src]+b)) * hv[src(e),:] )
// pd[v] = nf[v]·W_edge[0:D], ps[v] = nf[v]·W_edge[D:2D]
// hv = leaky_relu(nf @ W_node + b_node)

// ---------------- per-node edge-projection scalars ----------------
__global__ __launch_bounds__(256) void edge_proj_kernel(
    const float* __restrict__ nf, const float* __restrict__ We,
    const float* __restrict__ be, float* __restrict__ pd,
    float* __restrict__ ps, int nN) {
  int v = (int)((blockIdx.x * blockDim.x + threadIdx.x) >> 6);
  int lane = threadIdx.x & 63;
  if (v >= nN) return;
  const float* row = nf + (size_t)v * 128;
  float a0 = row[lane], a1 = row[lane + 64];
  float pdv = a0 * We[lane] + a1 * We[lane + 64];
  float psv = a0 * We[128 + lane] + a1 * We[192 + lane];
#pragma unroll
  for (int o = 32; o; o >>= 1) {
    pdv += __shfl_xor(pdv, o);
    psv += __shfl_xor(psv, o);
  }
  if (lane == 0) {
    pd[v] = pdv + be[0];  // fold bias into pd (added once per edge)
    ps[v] = psv;
  }
}

// ---------------- hv = leaky_relu(nf @ W_node + b) ----------------
// block = 256 threads, 32 rows x 128 cols per block, K=128.
__global__ __launch_bounds__(256) void hv_kernel(
    const float* __restrict__ nf, const float* __restrict__ Wn,
    const float* __restrict__ bn, float* __restrict__ hv, int nN) {
  __shared__ float As[32 * 128];
  int row0 = blockIdx.x * 32;
  int t = threadIdx.x;
  // stage A tile (guard tail rows)
  for (int i = t * 4; i < 32 * 128; i += 256 * 4) {
    int r = i >> 7;
    int gr = row0 + r;
    float4 val = make_float4(0.f, 0.f, 0.f, 0.f);
    if (gr < nN) val = *reinterpret_cast<const float4*>(nf + (size_t)gr * 128 + (i & 127));
    *reinterpret_cast<float4*>(As + i) = val;
  }
  __syncthreads();
  int c = t & 127, half = t >> 7;
  float acc[16];
#pragma unroll
  for (int r = 0; r < 16; ++r) acc[r] = 0.f;
  const float4* As4 = reinterpret_cast<const float4*>(As + (half * 16) * 128);
  for (int k4 = 0; k4 < 32; ++k4) {
    int k = k4 * 4;
    float w0 = Wn[(k + 0) * 128 + c];
    float w1 = Wn[(k + 1) * 128 + c];
    float w2 = Wn[(k + 2) * 128 + c];
    float w3 = Wn[(k + 3) * 128 + c];
#pragma unroll
    for (int r = 0; r < 16; ++r) {
      float4 a4 = As4[r * 32 + k4];  // wave-uniform address -> LDS broadcast
      acc[r] += a4.x * w0 + a4.y * w1 + a4.z * w2 + a4.w * w3;
    }
  }
  float bb = bn[c];
#pragma unroll
  for (int r = 0; r < 16; ++r) {
    int gr = row0 + half * 16 + r;
    if (gr < nN) {
      float x = acc[r] + bb;
      hv[(size_t)gr * 128 + c] = x > 0.f ? x : 0.01f * x;
    }
  }
}

// ---------------- CSR build: count, 3-kernel scan, scatter ----------------
__global__ void count_kernel(const int* __restrict__ dst, int* __restrict__ deg, int nE) {
  int e = blockIdx.x * blockDim.x + threadIdx.x;
  if (e < nE) atomicAdd(&deg[dst[e]], 1);
}

__global__ void scan_blocksum(const int* __restrict__ deg, int* __restrict__ bsum, int nN) {
  __shared__ int wsum[4];
  int base = blockIdx.x * 1024;
  int t = threadIdx.x;
  int s = 0;
  for (int i = 0; i < 4; ++i) {
    int idx = base + t + i * 256;
    if (idx < nN) s += deg[idx];
  }
#pragma unroll
  for (int o = 32; o; o >>= 1) s += __shfl_down(s, o);
  if ((t & 63) == 0) wsum[t >> 6] = s;
  __syncthreads();
  if (t == 0) bsum[blockIdx.x] = wsum[0] + wsum[1] + wsum[2] + wsum[3];
}

__global__ void scan_bsums(int* __restrict__ bsum, int nB) {
  // nB <= 64 (N <= 65536)
  int t = threadIdx.x;
  int v = (t < nB) ? bsum[t] : 0;
  int incl = v;
#pragma unroll
  for (int o = 1; o < 64; o <<= 1) {
    int x = __shfl_up(incl, o);
    if (t >= o) incl += x;
  }
  if (t < nB) bsum[t] = incl - v;  // exclusive
}

__global__ void scan_final(const int* __restrict__ deg, const int* __restrict__ bsum,
                           int* __restrict__ offs, int* __restrict__ cursor, int nN) {
  __shared__ int wtot[4];
  int base = blockIdx.x * 1024;
  int t = threadIdx.x;
  int idx0 = base + t * 4;
  int v[4];
#pragma unroll
  for (int i = 0; i < 4; ++i) {
    int idx = idx0 + i;
    v[i] = (idx < nN) ? deg[idx] : 0;
  }
  int tsum = v[0] + v[1] + v[2] + v[3];
  int lane = t & 63, w = t >> 6;
  int incl = tsum;
#pragma unroll
  for (int o = 1; o < 64; o <<= 1) {
    int x = __shfl_up(incl, o);
    if (lane >= o) incl += x;
  }
  if (lane == 63) wtot[w] = incl;
  __syncthreads();
  int wbase = 0;
  for (int i = 0; i < w; ++i) wbase += wtot[i];
  int run = bsum[blockIdx.x] + wbase + incl - tsum;
#pragma unroll
  for (int i = 0; i < 4; ++i) {
    int idx = idx0 + i;
    if (idx < nN) {
      offs[idx] = run;
      cursor[idx] = run;
      run += v[i];
      if (idx == nN - 1) offs[nN] = run;
    }
  }
}

__global__ void scatter_kernel(const int* __restrict__ src, const int* __restrict__ dst,
                               int* __restrict__ cursor, int* __restrict__ ssorted, int nE) {
  int e = blockIdx.x * blockDim.x + threadIdx.x;
  if (e < nE) {
    int d = dst[e];
    int pos = atomicAdd(&cursor[d], 1);
    ssorted[pos] = src[e];
  }
}

// ---------------- per-node softmax + weighted aggregation ----------------
// one wave per destination node; lane handles features (lane, lane+64)
__global__ __launch_bounds__(256) void aggregate_kernel(
    const int* __restrict__ offs, const int* __restrict__ ssorted,
    const float* __restrict__ pd, const float* __restrict__ ps,
    const float* __restrict__ hv, float* __restrict__ out, int nN) {
  int v = blockIdx.x * 4 + (threadIdx.x >> 6);
  if (v >= nN) return;
  int lane = threadIdx.x & 63;
  int s0 = offs[v], e1 = offs[v + 1];
  size_t obase = (size_t)v * 128;
  if (e1 == s0) {  // no incoming edges: c = 0 -> elu(0) = 0
    out[obase + lane] = 0.f;
    out[obase + 64 + lane] = 0.f;
    return;
  }
  float pdv = pd[v];
  // pass 1: segment max (lane-parallel)
  float m = -1e30f;
  for (int i = s0 + lane; i < e1; i += 64) {
    int u = ssorted[i];
    float x = pdv + ps[u];
    x = x > 0.f ? x : 0.01f * x;
    m = fmaxf(m, x);
  }
#pragma unroll
  for (int o = 32; o; o >>= 1) m = fmaxf(m, __shfl_xor(m, o));
  // pass 2: segment sum of exp
  float ssum = 0.f;
  for (int i = s0 + lane; i < e1; i += 64) {
    int u = ssorted[i];
    float x = pdv + ps[u];
    x = x > 0.f ? x : 0.01f * x;
    ssum += __expf(x - m);
  }
#pragma unroll
  for (int o = 32; o; o >>= 1) ssum += __shfl_xor(ssum, o);
  float rinv = 1.f / ssum;  // ssum >= 1 always (max element contributes exp(0))
  // pass 3: weighted gather-accumulate, wave reads hv row coalesced
  float acc0 = 0.f, acc1 = 0.f;
  for (int i = s0; i < e1; ++i) {
    int u = ssorted[i];
    float x = pdv + ps[u];
    x = x > 0.f ? x : 0.01f * x;
    float a = __expf(x - m) * rinv;
    const float* hr = hv + (size_t)u * 128;
    acc0 += a * hr[lane];
    acc1 += a * hr[lane + 64];
  }
  out[obase + lane] = acc0 > 0.f ? acc0 : expm1f(acc0);
  out[obase + 64 + lane] = acc1 > 0.f ? acc1 : expm1f(acc1);
}

extern "C" void kernel_launch(void* const* d_in, const int* in_sizes, int n_in,
                              void* d_out, int out_size, void* d_ws, size_t ws_size,
                              hipStream_t stream) {
  const float* nf = (const float*)d_in[0];
  const int* src = (const int*)d_in[1];
  const int* dst = (const int*)d_in[2];
  const float* We = (const float*)d_in[3];
  const float* be = (const float*)d_in[4];
  const float* Wn = (const float*)d_in[5];
  const float* bn = (const float*)d_in[6];
  float* out = (float*)d_out;
  int nN = in_sizes[0] / 128;
  int nE = in_sizes[1];

  // workspace carve (all 4-byte types; ~30 MB total)
  float* hv = (float*)d_ws;
  float* pd = hv + (size_t)nN * 128;
  float* ps = pd + nN;
  int* deg = (int*)(ps + nN);
  int* offs = deg + nN;       // nN+1
  int* cursor = offs + nN + 1;
  int* bsum = cursor + nN;    // <=256
  int* ssorted = bsum + 256;  // nE

  hipMemsetAsync(deg, 0, (size_t)nN * sizeof(int), stream);

  edge_proj_kernel<<<(nN + 3) / 4, 256, 0, stream>>>(nf, We, be, pd, ps, nN);
  hv_kernel<<<(nN + 31) / 32, 256, 0, stream>>>(nf, Wn, bn, hv, nN);
  count_kernel<<<(nE + 255) / 256, 256, 0, stream>>>(dst, deg, nE);
  int nB = (nN + 1023) / 1024;
  scan_blocksum<<<nB, 256, 0, stream>>>(deg, bsum, nN);
  scan_bsums<<<1, 64, 0, stream>>>(bsum, nB);
  scan_final<<<nB, 256, 0, stream>>>(deg, bsum, offs, cursor, nN);
  scatter_kernel<<<(nE + 255) / 256, 256, 0, stream>>>(src, dst, cursor, ssorted, nE);
  aggregate_kernel<<<(nN + 3) / 4, 256, 0, stream>>>(offs, ssorted, pd, ps, hv, out, nN);
}

// Round 2
// 223.026 us; speedup vs baseline: 1.0995x; 1.0995x over previous
//
#include <hip/hip_runtime.h>
#include <hip/hip_bf16.h>
#include <math.h>

// Problem: N=50000 nodes, E=800000 edges, D=G=128.
// out[v,:] = elu( sum_{e: dst(e)=v} softmax_e(leaky(pd[dst]+ps[src]+b)) * hv[src(e),:] )
// pd[v] = nf[v]·W_edge[0:D] (+ b_edge), ps[v] = nf[v]·W_edge[D:2D]
// hv = leaky_relu(nf @ W_node + b_node), stored as packed bf16 pairs (u32).

static __device__ __forceinline__ unsigned pack_bf16(float x0, float x1) {
  unsigned u0 = (unsigned)__bfloat16_as_ushort(__float2bfloat16(x0));
  unsigned u1 = (unsigned)__bfloat16_as_ushort(__float2bfloat16(x1));
  return u0 | (u1 << 16);
}

// ---------------- fused: hv GEMM (bf16 out) + per-node edge scalars ----------------
// block = 256 threads, 32 rows x 128 cols per block, K=128.
__global__ __launch_bounds__(256) void hv_kernel(
    const float* __restrict__ nf, const float* __restrict__ Wn,
    const float* __restrict__ bn, const float* __restrict__ We,
    const float* __restrict__ be, unsigned* __restrict__ hv2,
    float* __restrict__ pd, float* __restrict__ ps, int nN) {
  __shared__ float As[32 * 128];
  int row0 = blockIdx.x * 32;
  int t = threadIdx.x;
  // stage A tile (guard tail rows)
  for (int i = t * 4; i < 32 * 128; i += 256 * 4) {
    int r = i >> 7;
    int gr = row0 + r;
    float4 val = make_float4(0.f, 0.f, 0.f, 0.f);
    if (gr < nN) val = *reinterpret_cast<const float4*>(nf + (size_t)gr * 128 + (i & 127));
    *reinterpret_cast<float4*>(As + i) = val;
  }
  __syncthreads();
  int lane = t & 63, w = t >> 6;
  // edge-projection scalars for this tile's 32 rows (wave w handles rows w*8..w*8+7)
  for (int rr = 0; rr < 8; ++rr) {
    int r = w * 8 + rr;
    int gr = row0 + r;
    float a0 = As[r * 128 + lane], a1 = As[r * 128 + 64 + lane];
    float pdv = a0 * We[lane] + a1 * We[64 + lane];
    float psv = a0 * We[128 + lane] + a1 * We[192 + lane];
#pragma unroll
    for (int o = 32; o; o >>= 1) {
      pdv += __shfl_xor(pdv, o);
      psv += __shfl_xor(psv, o);
    }
    if (lane == 0 && gr < nN) {
      pd[gr] = pdv + be[0];  // bias folded here (added once per edge)
      ps[gr] = psv;
    }
  }
  // GEMM: thread owns 8 rows (group rg) x 2 cols (2*cp, 2*cp+1)
  int cp = t & 63, rg = t >> 6;
  float acc0[8], acc1[8];
#pragma unroll
  for (int r = 0; r < 8; ++r) acc0[r] = acc1[r] = 0.f;
  const float4* As4 = reinterpret_cast<const float4*>(As + (rg * 8) * 128);
  for (int k4 = 0; k4 < 32; ++k4) {
    int k = k4 * 4;
    float2 w0 = *reinterpret_cast<const float2*>(Wn + (size_t)(k + 0) * 128 + 2 * cp);
    float2 w1 = *reinterpret_cast<const float2*>(Wn + (size_t)(k + 1) * 128 + 2 * cp);
    float2 w2 = *reinterpret_cast<const float2*>(Wn + (size_t)(k + 2) * 128 + 2 * cp);
    float2 w3 = *reinterpret_cast<const float2*>(Wn + (size_t)(k + 3) * 128 + 2 * cp);
#pragma unroll
    for (int r = 0; r < 8; ++r) {
      float4 a4 = As4[r * 32 + k4];  // wave-uniform address -> LDS broadcast
      acc0[r] += a4.x * w0.x + a4.y * w1.x + a4.z * w2.x + a4.w * w3.x;
      acc1[r] += a4.x * w0.y + a4.y * w1.y + a4.z * w2.y + a4.w * w3.y;
    }
  }
  float2 bb = *reinterpret_cast<const float2*>(bn + 2 * cp);
#pragma unroll
  for (int r = 0; r < 8; ++r) {
    int gr = row0 + rg * 8 + r;
    if (gr < nN) {
      float x0 = acc0[r] + bb.x, x1 = acc1[r] + bb.y;
      x0 = x0 > 0.f ? x0 : 0.01f * x0;
      x1 = x1 > 0.f ? x1 : 0.01f * x1;
      hv2[(size_t)gr * 64 + cp] = pack_bf16(x0, x1);
    }
  }
}

// ---------------- CSR build: count, 3-kernel scan, scatter ----------------
__global__ void count_kernel(const int* __restrict__ dst, int* __restrict__ deg, int nE) {
  int e = blockIdx.x * blockDim.x + threadIdx.x;
  if (e < nE) atomicAdd(&deg[dst[e]], 1);
}

__global__ void scan_blocksum(const int* __restrict__ deg, int* __restrict__ bsum, int nN) {
  __shared__ int wsum[4];
  int base = blockIdx.x * 1024;
  int t = threadIdx.x;
  int s = 0;
  for (int i = 0; i < 4; ++i) {
    int idx = base + t + i * 256;
    if (idx < nN) s += deg[idx];
  }
#pragma unroll
  for (int o = 32; o; o >>= 1) s += __shfl_down(s, o);
  if ((t & 63) == 0) wsum[t >> 6] = s;
  __syncthreads();
  if (t == 0) bsum[blockIdx.x] = wsum[0] + wsum[1] + wsum[2] + wsum[3];
}

__global__ void scan_bsums(int* __restrict__ bsum, int nB) {
  // nB <= 64 (N <= 65536)
  int t = threadIdx.x;
  int v = (t < nB) ? bsum[t] : 0;
  int incl = v;
#pragma unroll
  for (int o = 1; o < 64; o <<= 1) {
    int x = __shfl_up(incl, o);
    if (t >= o) incl += x;
  }
  if (t < nB) bsum[t] = incl - v;  // exclusive
}

__global__ void scan_final(const int* __restrict__ deg, const int* __restrict__ bsum,
                           int* __restrict__ offs, int* __restrict__ cursor, int nN) {
  __shared__ int wtot[4];
  int base = blockIdx.x * 1024;
  int t = threadIdx.x;
  int idx0 = base + t * 4;
  int v[4];
#pragma unroll
  for (int i = 0; i < 4; ++i) {
    int idx = idx0 + i;
    v[i] = (idx < nN) ? deg[idx] : 0;
  }
  int tsum = v[0] + v[1] + v[2] + v[3];
  int lane = t & 63, w = t >> 6;
  int incl = tsum;
#pragma unroll
  for (int o = 1; o < 64; o <<= 1) {
    int x = __shfl_up(incl, o);
    if (lane >= o) incl += x;
  }
  if (lane == 63) wtot[w] = incl;
  __syncthreads();
  int wbase = 0;
  for (int i = 0; i < w; ++i) wbase += wtot[i];
  int run = bsum[blockIdx.x] + wbase + incl - tsum;
#pragma unroll
  for (int i = 0; i < 4; ++i) {
    int idx = idx0 + i;
    if (idx < nN) {
      offs[idx] = run;
      cursor[idx] = run;
      run += v[i];
      if (idx == nN - 1) offs[nN] = run;
    }
  }
}

// scatter edges into dst-CSR order; also precompute the leaky logit per edge
__global__ void scatter_kernel(const int* __restrict__ src, const int* __restrict__ dst,
                               const float* __restrict__ pd, const float* __restrict__ ps,
                               int* __restrict__ cursor, int* __restrict__ ssorted,
                               float* __restrict__ xs, int nE) {
  int e = blockIdx.x * blockDim.x + threadIdx.x;
  if (e < nE) {
    int d = dst[e], s = src[e];
    int pos = atomicAdd(&cursor[d], 1);
    float x = pd[d] + ps[s];
    ssorted[pos] = s;
    xs[pos] = x > 0.f ? x : 0.01f * x;
  }
}

// ---------------- per-node softmax + weighted aggregation ----------------
// one wave per destination node; lane handles feature pair (2*lane, 2*lane+1)
__global__ __launch_bounds__(256) void aggregate_kernel(
    const int* __restrict__ offs, const int* __restrict__ ssorted,
    const float* __restrict__ xs, const unsigned* __restrict__ hv2,
    float* __restrict__ out, int nN) {
  int v = blockIdx.x * 4 + (threadIdx.x >> 6);
  if (v >= nN) return;
  int lane = threadIdx.x & 63;
  int s0 = offs[v], e1 = offs[v + 1];
  float2* out2 = reinterpret_cast<float2*>(out) + (size_t)v * 64 + lane;
  if (e1 == s0) {  // no incoming edges: c = 0 -> elu(0) = 0
    *out2 = make_float2(0.f, 0.f);
    return;
  }
  // pass 1: segment max over contiguous logits
  float m = -1e30f;
  for (int i = s0 + lane; i < e1; i += 64) m = fmaxf(m, xs[i]);
#pragma unroll
  for (int o = 32; o; o >>= 1) m = fmaxf(m, __shfl_xor(m, o));
  // pass 2: segment sum of exp
  float ssum = 0.f;
  for (int i = s0 + lane; i < e1; i += 64) ssum += __expf(xs[i] - m);
#pragma unroll
  for (int o = 32; o; o >>= 1) ssum += __shfl_xor(ssum, o);
  float rinv = 1.f / ssum;  // ssum >= 1 (max element contributes exp(0))
  // pass 3: weighted gather-accumulate; wave reads 256B bf16 row coalesced
  float acc0 = 0.f, acc1 = 0.f;
  for (int i = s0; i < e1; ++i) {
    int u = ssorted[i];
    float a = __expf(xs[i] - m) * rinv;
    unsigned pk = hv2[(size_t)u * 64 + lane];
    float f0 = __uint_as_float(pk << 16);
    float f1 = __uint_as_float(pk & 0xffff0000u);
    acc0 += a * f0;
    acc1 += a * f1;
  }
  float e0 = acc0 > 0.f ? acc0 : expm1f(acc0);
  float e1v = acc1 > 0.f ? acc1 : expm1f(acc1);
  *out2 = make_float2(e0, e1v);
}

extern "C" void kernel_launch(void* const* d_in, const int* in_sizes, int n_in,
                              void* d_out, int out_size, void* d_ws, size_t ws_size,
                              hipStream_t stream) {
  const float* nf = (const float*)d_in[0];
  const int* src = (const int*)d_in[1];
  const int* dst = (const int*)d_in[2];
  const float* We = (const float*)d_in[3];
  const float* be = (const float*)d_in[4];
  const float* Wn = (const float*)d_in[5];
  const float* bn = (const float*)d_in[6];
  float* out = (float*)d_out;
  int nN = in_sizes[0] / 128;
  int nE = in_sizes[1];

  // workspace carve (all 4-byte types; ~20 MB total)
  unsigned* hv2 = (unsigned*)d_ws;            // nN*64
  float* pd = (float*)(hv2 + (size_t)nN * 64);
  float* ps = pd + nN;
  int* deg = (int*)(ps + nN);
  int* offs = deg + nN;       // nN+1
  int* cursor = offs + nN + 1;
  int* bsum = cursor + nN;    // <=256
  int* ssorted = bsum + 256;  // nE
  float* xs = (float*)(ssorted + nE);  // nE

  hipMemsetAsync(deg, 0, (size_t)nN * sizeof(int), stream);

  hv_kernel<<<(nN + 31) / 32, 256, 0, stream>>>(nf, Wn, bn, We, be, hv2, pd, ps, nN);
  count_kernel<<<(nE + 255) / 256, 256, 0, stream>>>(dst, deg, nE);
  int nB = (nN + 1023) / 1024;
  scan_blocksum<<<nB, 256, 0, stream>>>(deg, bsum, nN);
  scan_bsums<<<1, 64, 0, stream>>>(bsum, nB);
  scan_final<<<nB, 256, 0, stream>>>(deg, bsum, offs, cursor, nN);
  scatter_kernel<<<(nE + 255) / 256, 256, 0, stream>>>(src, dst, pd, ps, cursor, ssorted, xs, nE);
  aggregate_kernel<<<(nN + 3) / 4, 256, 0, stream>>>(offs, ssorted, xs, hv2, out, nN);
}

// Round 3
// 169.837 us; speedup vs baseline: 1.4438x; 1.3132x over previous
//
#include <hip/hip_runtime.h>
#include <hip/hip_bf16.h>
#include <math.h>

// Problem: N=50000 nodes, E=800000 edges, D=G=128.
// out[v,:] = elu( sum_{e: dst(e)=v} softmax_e(leaky(pd[dst]+ps[src]+b)) * hv[src(e),:] )
// pd[v] = nf[v]·W_edge[0:D] (+ b_edge), ps[v] = nf[v]·W_edge[D:2D]
// hv = leaky_relu(nf @ W_node + b_node), stored as packed bf16 pairs (u32).

static __device__ __forceinline__ unsigned pack_bf16(float x0, float x1) {
  unsigned u0 = (unsigned)__bfloat16_as_ushort(__float2bfloat16(x0));
  unsigned u1 = (unsigned)__bfloat16_as_ushort(__float2bfloat16(x1));
  return u0 | (u1 << 16);
}

// ---------------- fused: hv GEMM (bf16 out) + per-node edge scalars ----------------
// block = 256 threads, 32 rows x 128 cols per block, K=128.
__global__ __launch_bounds__(256) void hv_kernel(
    const float* __restrict__ nf, const float* __restrict__ Wn,
    const float* __restrict__ bn, const float* __restrict__ We,
    const float* __restrict__ be, unsigned* __restrict__ hv2,
    float* __restrict__ pd, float* __restrict__ ps, int nN) {
  __shared__ float As[32 * 128];
  int row0 = blockIdx.x * 32;
  int t = threadIdx.x;
  for (int i = t * 4; i < 32 * 128; i += 256 * 4) {
    int r = i >> 7;
    int gr = row0 + r;
    float4 val = make_float4(0.f, 0.f, 0.f, 0.f);
    if (gr < nN) val = *reinterpret_cast<const float4*>(nf + (size_t)gr * 128 + (i & 127));
    *reinterpret_cast<float4*>(As + i) = val;
  }
  __syncthreads();
  int lane = t & 63, w = t >> 6;
  // edge-projection scalars for this tile's 32 rows (wave w handles rows w*8..w*8+7)
  for (int rr = 0; rr < 8; ++rr) {
    int r = w * 8 + rr;
    int gr = row0 + r;
    float a0 = As[r * 128 + lane], a1 = As[r * 128 + 64 + lane];
    float pdv = a0 * We[lane] + a1 * We[64 + lane];
    float psv = a0 * We[128 + lane] + a1 * We[192 + lane];
#pragma unroll
    for (int o = 32; o; o >>= 1) {
      pdv += __shfl_xor(pdv, o);
      psv += __shfl_xor(psv, o);
    }
    if (lane == 0 && gr < nN) {
      pd[gr] = pdv + be[0];  // bias folded here (added once per edge)
      ps[gr] = psv;
    }
  }
  // GEMM: thread owns 8 rows (group rg) x 2 cols (2*cp, 2*cp+1)
  int cp = t & 63, rg = t >> 6;
  float acc0[8], acc1[8];
#pragma unroll
  for (int r = 0; r < 8; ++r) acc0[r] = acc1[r] = 0.f;
  const float4* As4 = reinterpret_cast<const float4*>(As + (rg * 8) * 128);
  for (int k4 = 0; k4 < 32; ++k4) {
    int k = k4 * 4;
    float2 w0 = *reinterpret_cast<const float2*>(Wn + (size_t)(k + 0) * 128 + 2 * cp);
    float2 w1 = *reinterpret_cast<const float2*>(Wn + (size_t)(k + 1) * 128 + 2 * cp);
    float2 w2 = *reinterpret_cast<const float2*>(Wn + (size_t)(k + 2) * 128 + 2 * cp);
    float2 w3 = *reinterpret_cast<const float2*>(Wn + (size_t)(k + 3) * 128 + 2 * cp);
#pragma unroll
    for (int r = 0; r < 8; ++r) {
      float4 a4 = As4[r * 32 + k4];  // wave-uniform address -> LDS broadcast
      acc0[r] += a4.x * w0.x + a4.y * w1.x + a4.z * w2.x + a4.w * w3.x;
      acc1[r] += a4.x * w0.y + a4.y * w1.y + a4.z * w2.y + a4.w * w3.y;
    }
  }
  float2 bb = *reinterpret_cast<const float2*>(bn + 2 * cp);
#pragma unroll
  for (int r = 0; r < 8; ++r) {
    int gr = row0 + rg * 8 + r;
    if (gr < nN) {
      float x0 = acc0[r] + bb.x, x1 = acc1[r] + bb.y;
      x0 = x0 > 0.f ? x0 : 0.01f * x0;
      x1 = x1 > 0.f ? x1 : 0.01f * x1;
      hv2[(size_t)gr * 64 + cp] = pack_bf16(x0, x1);
    }
  }
}

// ---------------- CSR build: count, 3-kernel scan, scatter ----------------
__global__ void count_kernel(const int* __restrict__ dst, int* __restrict__ deg, int nE) {
  int e = blockIdx.x * blockDim.x + threadIdx.x;
  if (e < nE) atomicAdd(&deg[dst[e]], 1);
}

__global__ void scan_blocksum(const int* __restrict__ deg, int* __restrict__ bsum, int nN) {
  __shared__ int wsum[4];
  int base = blockIdx.x * 1024;
  int t = threadIdx.x;
  int s = 0;
  for (int i = 0; i < 4; ++i) {
    int idx = base + t + i * 256;
    if (idx < nN) s += deg[idx];
  }
#pragma unroll
  for (int o = 32; o; o >>= 1) s += __shfl_down(s, o);
  if ((t & 63) == 0) wsum[t >> 6] = s;
  __syncthreads();
  if (t == 0) bsum[blockIdx.x] = wsum[0] + wsum[1] + wsum[2] + wsum[3];
}

__global__ void scan_bsums(int* __restrict__ bsum, int nB) {
  // nB <= 64 (N <= 65536)
  int t = threadIdx.x;
  int v = (t < nB) ? bsum[t] : 0;
  int incl = v;
#pragma unroll
  for (int o = 1; o < 64; o <<= 1) {
    int x = __shfl_up(incl, o);
    if (t >= o) incl += x;
  }
  if (t < nB) bsum[t] = incl - v;  // exclusive
}

__global__ void scan_final(const int* __restrict__ deg, const int* __restrict__ bsum,
                           int* __restrict__ offs, int* __restrict__ cursor, int nN) {
  __shared__ int wtot[4];
  int base = blockIdx.x * 1024;
  int t = threadIdx.x;
  int idx0 = base + t * 4;
  int v[4];
#pragma unroll
  for (int i = 0; i < 4; ++i) {
    int idx = idx0 + i;
    v[i] = (idx < nN) ? deg[idx] : 0;
  }
  int tsum = v[0] + v[1] + v[2] + v[3];
  int lane = t & 63, w = t >> 6;
  int incl = tsum;
#pragma unroll
  for (int o = 1; o < 64; o <<= 1) {
    int x = __shfl_up(incl, o);
    if (lane >= o) incl += x;
  }
  if (lane == 63) wtot[w] = incl;
  __syncthreads();
  int wbase = 0;
  for (int i = 0; i < w; ++i) wbase += wtot[i];
  int run = bsum[blockIdx.x] + wbase + incl - tsum;
#pragma unroll
  for (int i = 0; i < 4; ++i) {
    int idx = idx0 + i;
    if (idx < nN) {
      offs[idx] = run;
      cursor[idx] = run;
      run += v[i];
      if (idx == nN - 1) offs[nN] = run;
    }
  }
}

// scatter edges into dst-CSR order; pack (src, leaky-logit) into one int2
__global__ void scatter_kernel(const int* __restrict__ src, const int* __restrict__ dst,
                               const float* __restrict__ pd, const float* __restrict__ ps,
                               int* __restrict__ cursor, int2* __restrict__ ssx, int nE) {
  int e = blockIdx.x * blockDim.x + threadIdx.x;
  if (e < nE) {
    int d = dst[e], s = src[e];
    int pos = atomicAdd(&cursor[d], 1);
    float x = pd[d] + ps[s];
    x = x > 0.f ? x : 0.01f * x;
    ssx[pos] = make_int2(s, __float_as_int(x));
  }
}

// ---------------- per-node softmax + weighted aggregation ----------------
// one wave per destination node; lane handles feature pair (2*lane, 2*lane+1).
// Fast path (deg<=64): edge list held in registers, 8 gathers in flight.
__global__ __launch_bounds__(256) void aggregate_kernel(
    const int* __restrict__ offs, const int2* __restrict__ ssx,
    const unsigned* __restrict__ hv2, float* __restrict__ out, int nN) {
  int v = blockIdx.x * 4 + (threadIdx.x >> 6);
  if (v >= nN) return;
  int lane = threadIdx.x & 63;
  int s0 = offs[v], e1 = offs[v + 1];
  int deg = e1 - s0;
  float2* out2 = reinterpret_cast<float2*>(out) + (size_t)v * 64 + lane;
  if (deg == 0) {  // no incoming edges: c = 0 -> elu(0) = 0
    *out2 = make_float2(0.f, 0.f);
    return;
  }
  float acc0 = 0.f, acc1 = 0.f;
  if (deg <= 64) {
    // one edge per lane, everything else via shuffles
    int2 sx = ssx[s0 + (lane < deg ? lane : 0)];
    int se = sx.x;
    float xe = __int_as_float(sx.y);
    float m = lane < deg ? xe : -1e30f;
#pragma unroll
    for (int o = 32; o; o >>= 1) m = fmaxf(m, __shfl_xor(m, o));
    float ex = lane < deg ? __expf(xe - m) : 0.f;
    float ssum = ex;
#pragma unroll
    for (int o = 32; o; o >>= 1) ssum += __shfl_xor(ssum, o);
    float rinv = 1.f / ssum;  // ssum >= 1 (max element contributes exp(0))
    for (int i0 = 0; i0 < deg; i0 += 8) {
      int u[8];
#pragma unroll
      for (int j = 0; j < 8; ++j) {
        int jj = i0 + j;
        u[j] = __shfl(se, jj < deg ? jj : 0);
      }
      unsigned pk[8];
#pragma unroll
      for (int j = 0; j < 8; ++j) pk[j] = hv2[(u[j] << 6) + lane];  // 8 gathers in flight
      float aw[8];
#pragma unroll
      for (int j = 0; j < 8; ++j) {
        int jj = i0 + j;
        float exj = __shfl(ex, jj < deg ? jj : 0);
        aw[j] = jj < deg ? exj * rinv : 0.f;
      }
#pragma unroll
      for (int j = 0; j < 8; ++j) {
        acc0 += aw[j] * __uint_as_float(pk[j] << 16);
        acc1 += aw[j] * __uint_as_float(pk[j] & 0xffff0000u);
      }
    }
  } else {
    // rare fallback: 3-pass over global edge list
    float m = -1e30f;
    for (int i = s0 + lane; i < e1; i += 64) m = fmaxf(m, __int_as_float(ssx[i].y));
#pragma unroll
    for (int o = 32; o; o >>= 1) m = fmaxf(m, __shfl_xor(m, o));
    float ssum = 0.f;
    for (int i = s0 + lane; i < e1; i += 64) ssum += __expf(__int_as_float(ssx[i].y) - m);
#pragma unroll
    for (int o = 32; o; o >>= 1) ssum += __shfl_xor(ssum, o);
    float rinv = 1.f / ssum;
    for (int i0 = s0; i0 < e1; i0 += 8) {
      int u[8];
      float aw[8];
      unsigned pk[8];
#pragma unroll
      for (int j = 0; j < 8; ++j) {
        int idx = i0 + j;
        bool ok = idx < e1;
        int2 sx = ssx[ok ? idx : s0];
        u[j] = sx.x;
        aw[j] = ok ? __expf(__int_as_float(sx.y) - m) * rinv : 0.f;
      }
#pragma unroll
      for (int j = 0; j < 8; ++j) pk[j] = hv2[(u[j] << 6) + lane];
#pragma unroll
      for (int j = 0; j < 8; ++j) {
        acc0 += aw[j] * __uint_as_float(pk[j] << 16);
        acc1 += aw[j] * __uint_as_float(pk[j] & 0xffff0000u);
      }
    }
  }
  float e0 = acc0 > 0.f ? acc0 : expm1f(acc0);
  float e1v = acc1 > 0.f ? acc1 : expm1f(acc1);
  *out2 = make_float2(e0, e1v);
}

extern "C" void kernel_launch(void* const* d_in, const int* in_sizes, int n_in,
                              void* d_out, int out_size, void* d_ws, size_t ws_size,
                              hipStream_t stream) {
  const float* nf = (const float*)d_in[0];
  const int* src = (const int*)d_in[1];
  const int* dst = (const int*)d_in[2];
  const float* We = (const float*)d_in[3];
  const float* be = (const float*)d_in[4];
  const float* Wn = (const float*)d_in[5];
  const float* bn = (const float*)d_in[6];
  float* out = (float*)d_out;
  int nN = in_sizes[0] / 128;
  int nE = in_sizes[1];

  // workspace carve (~20 MB); ssx first for 8-byte alignment
  int2* ssx = (int2*)d_ws;                       // nE
  unsigned* hv2 = (unsigned*)(ssx + nE);         // nN*64
  float* pd = (float*)(hv2 + (size_t)nN * 64);
  float* ps = pd + nN;
  int* deg = (int*)(ps + nN);
  int* offs = deg + nN;       // nN+1
  int* cursor = offs + nN + 1;
  int* bsum = cursor + nN;    // <=256

  hipMemsetAsync(deg, 0, (size_t)nN * sizeof(int), stream);

  hv_kernel<<<(nN + 31) / 32, 256, 0, stream>>>(nf, Wn, bn, We, be, hv2, pd, ps, nN);
  count_kernel<<<(nE + 255) / 256, 256, 0, stream>>>(dst, deg, nE);
  int nB = (nN + 1023) / 1024;
  scan_blocksum<<<nB, 256, 0, stream>>>(deg, bsum, nN);
  scan_bsums<<<1, 64, 0, stream>>>(bsum, nB);
  scan_final<<<nB, 256, 0, stream>>>(deg, bsum, offs, cursor, nN);
  scatter_kernel<<<(nE + 255) / 256, 256, 0, stream>>>(src, dst, pd, ps, cursor, ssx, nE);
  aggregate_kernel<<<(nN + 3) / 4, 256, 0, stream>>>(offs, ssx, hv2, out, nN);
}

// Round 4
// 152.234 us; speedup vs baseline: 1.6108x; 1.1156x over previous
//
#include <hip/hip_runtime.h>
#include <hip/hip_bf16.h>
#include <math.h>

// Problem: N=50000 nodes, E=800000 edges, D=G=128.
// out[v,:] = elu( sum_{e: dst(e)=v} softmax_e(leaky(pd[dst]+ps[src]+b)) * hv[src(e),:] )
// pd[v] = nf[v]·W_edge[0:D] (+ b_edge), ps[v] = nf[v]·W_edge[D:2D]
// hv = leaky_relu(nf @ W_node + b_node) via bf16 MFMA, stored as packed bf16 pairs.

using bf16x8 = __attribute__((ext_vector_type(8))) __bf16;
using f32x4 = __attribute__((ext_vector_type(4))) float;

static __device__ __forceinline__ unsigned pack_bf16(float x0, float x1) {
  unsigned u0 = (unsigned)__bfloat16_as_ushort(__float2bfloat16(x0));
  unsigned u1 = (unsigned)__bfloat16_as_ushort(__float2bfloat16(x1));
  return u0 | (u1 << 16);
}

// ---- one-time: convert Wn (128x128 f32) to bf16, pre-swizzled into B-fragment order ----
// B frag for mfma_f32_16x16x32_bf16: lane l holds col=l&15, k=(l>>4)*8+j (j=0..7).
// wsw[((kstep*8+ct)*64 + l)*8 + j] = bf16(Wn[(kstep*32 + (l>>4)*8 + j)*128 + ct*16 + (l&15)])
__global__ void wconv_kernel(const float* __restrict__ Wn, ushort* __restrict__ wsw) {
  int i = blockIdx.x * 256 + threadIdx.x;  // 0..16383
  int j = i & 7, l = (i >> 3) & 63, ct = (i >> 9) & 7, kstep = i >> 12;
  int k = kstep * 32 + ((l >> 4) << 3) + j;
  int c = ct * 16 + (l & 15);
  wsw[i] = __bfloat16_as_ushort(__float2bfloat16(Wn[k * 128 + c]));
}

// ---------------- fused: hv MFMA GEMM (bf16) + per-node edge scalars ----------------
// block = 256 threads (4 waves), 64 rows x 128 cols per block, K=128.
__global__ __launch_bounds__(256) void hv_mfma_kernel(
    const float* __restrict__ nf, const ushort* __restrict__ wsw,
    const float* __restrict__ bn, const float* __restrict__ We,
    const float* __restrict__ be, unsigned* __restrict__ hv2,
    float* __restrict__ pd, float* __restrict__ ps, int nN) {
  __shared__ unsigned Atile[64 * 64];  // 64 rows x 256B of bf16, XOR-swizzled 16B slots
  int row0 = blockIdx.x * 64;
  int t = threadIdx.x;
  // stage A tile: 1024 slots of 16B (8 bf16); thread handles 4 slots
#pragma unroll
  for (int ss = 0; ss < 4; ++ss) {
    int s = t + ss * 256;
    int r = s >> 4, sl = s & 15;
    int gr = row0 + r;
    float4 f0 = make_float4(0.f, 0.f, 0.f, 0.f), f1 = f0;
    if (gr < nN) {
      const float4* p = reinterpret_cast<const float4*>(nf + (size_t)gr * 128 + sl * 8);
      f0 = p[0];
      f1 = p[1];
    }
    uint4 pk;
    pk.x = pack_bf16(f0.x, f0.y);
    pk.y = pack_bf16(f0.z, f0.w);
    pk.z = pack_bf16(f1.x, f1.y);
    pk.w = pack_bf16(f1.z, f1.w);
    int byte = r * 256 + ((sl * 16) ^ ((r & 7) << 4));  // T2 swizzle vs 16-way conflict
    *reinterpret_cast<uint4*>(reinterpret_cast<char*>(Atile) + byte) = pk;
  }
  __syncthreads();
  int lane = t & 63, w = t >> 6;
  // edge-projection scalars (fp32, reads nf from global -> L1-hot after staging)
  float we0 = We[lane], we1 = We[64 + lane], we2 = We[128 + lane], we3 = We[192 + lane];
  float bev = be[0];
  for (int rr = 0; rr < 16; ++rr) {
    int gr = row0 + w * 16 + rr;
    if (gr >= nN) break;  // wave-uniform
    const float* rowp = nf + (size_t)gr * 128;
    float a0 = rowp[lane], a1 = rowp[64 + lane];
    float pdv = a0 * we0 + a1 * we1;
    float psv = a0 * we2 + a1 * we3;
#pragma unroll
    for (int o = 32; o; o >>= 1) {
      pdv += __shfl_xor(pdv, o);
      psv += __shfl_xor(psv, o);
    }
    if (lane == 0) {
      pd[gr] = pdv + bev;  // bias folded (added once per edge)
      ps[gr] = psv;
    }
  }
  // MFMA: wave w owns rows w*16..w*16+15, 8 col-tiles of 16, K=128 (4 ksteps)
  f32x4 acc[8];
#pragma unroll
  for (int c = 0; c < 8; ++c) acc[c] = (f32x4){0.f, 0.f, 0.f, 0.f};
  int rl = w * 16 + (lane & 15);  // A row (local)
  const char* abase = reinterpret_cast<const char*>(Atile) + rl * 256;
  int ksel = (lane >> 4) * 16;  // byte offset of this lane's 8-k chunk
#pragma unroll
  for (int kstep = 0; kstep < 4; ++kstep) {
    int kb = kstep * 64 + ksel;
    bf16x8 afrag = *reinterpret_cast<const bf16x8*>(abase + (kb ^ ((rl & 7) << 4)));
#pragma unroll
    for (int ct = 0; ct < 8; ++ct) {
      bf16x8 bfrag = *reinterpret_cast<const bf16x8*>(wsw + ((size_t)((kstep * 8 + ct) * 64 + lane)) * 8);
      acc[ct] = __builtin_amdgcn_mfma_f32_16x16x32_bf16(afrag, bfrag, acc[ct], 0, 0, 0);
    }
  }
  // epilogue: D layout col=lane&15, row=(lane>>4)*4+reg; pack (c, c+1) via shfl
  int colbase = lane & 15;
  int rbase = row0 + w * 16 + ((lane >> 4) << 2);
#pragma unroll
  for (int ct = 0; ct < 8; ++ct) {
    int col = ct * 16 + colbase;
    float bb = bn[col];
#pragma unroll
    for (int r = 0; r < 4; ++r) {
      float x = acc[ct][r] + bb;
      x = x > 0.f ? x : 0.01f * x;
      float y = __shfl_xor(x, 1);
      int gr = rbase + r;
      if (!(lane & 1) && gr < nN)
        hv2[(size_t)gr * 64 + ct * 8 + (colbase >> 1)] = pack_bf16(x, y);
    }
  }
}

// ---------------- CSR build: count, 3-kernel scan, scatter ----------------
__global__ void count_kernel(const int* __restrict__ dst, int* __restrict__ deg, int nE) {
  int e = blockIdx.x * blockDim.x + threadIdx.x;
  if (e < nE) atomicAdd(&deg[dst[e]], 1);
}

__global__ void scan_blocksum(const int* __restrict__ deg, int* __restrict__ bsum, int nN) {
  __shared__ int wsum[4];
  int base = blockIdx.x * 1024;
  int t = threadIdx.x;
  int s = 0;
  for (int i = 0; i < 4; ++i) {
    int idx = base + t + i * 256;
    if (idx < nN) s += deg[idx];
  }
#pragma unroll
  for (int o = 32; o; o >>= 1) s += __shfl_down(s, o);
  if ((t & 63) == 0) wsum[t >> 6] = s;
  __syncthreads();
  if (t == 0) bsum[blockIdx.x] = wsum[0] + wsum[1] + wsum[2] + wsum[3];
}

__global__ void scan_bsums(int* __restrict__ bsum, int nB) {
  // nB <= 64 (N <= 65536)
  int t = threadIdx.x;
  int v = (t < nB) ? bsum[t] : 0;
  int incl = v;
#pragma unroll
  for (int o = 1; o < 64; o <<= 1) {
    int x = __shfl_up(incl, o);
    if (t >= o) incl += x;
  }
  if (t < nB) bsum[t] = incl - v;  // exclusive
}

__global__ void scan_final(const int* __restrict__ deg, const int* __restrict__ bsum,
                           int* __restrict__ offs, int* __restrict__ cursor, int nN) {
  __shared__ int wtot[4];
  int base = blockIdx.x * 1024;
  int t = threadIdx.x;
  int idx0 = base + t * 4;
  int v[4];
#pragma unroll
  for (int i = 0; i < 4; ++i) {
    int idx = idx0 + i;
    v[i] = (idx < nN) ? deg[idx] : 0;
  }
  int tsum = v[0] + v[1] + v[2] + v[3];
  int lane = t & 63, w = t >> 6;
  int incl = tsum;
#pragma unroll
  for (int o = 1; o < 64; o <<= 1) {
    int x = __shfl_up(incl, o);
    if (lane >= o) incl += x;
  }
  if (lane == 63) wtot[w] = incl;
  __syncthreads();
  int wbase = 0;
  for (int i = 0; i < w; ++i) wbase += wtot[i];
  int run = bsum[blockIdx.x] + wbase + incl - tsum;
#pragma unroll
  for (int i = 0; i < 4; ++i) {
    int idx = idx0 + i;
    if (idx < nN) {
      offs[idx] = run;
      cursor[idx] = run;
      run += v[i];
      if (idx == nN - 1) offs[nN] = run;
    }
  }
}

// scatter edges into dst-CSR order; pack (src, leaky-logit) into one int2
__global__ void scatter_kernel(const int* __restrict__ src, const int* __restrict__ dst,
                               const float* __restrict__ pd, const float* __restrict__ ps,
                               int* __restrict__ cursor, int2* __restrict__ ssx, int nE) {
  int e = blockIdx.x * blockDim.x + threadIdx.x;
  if (e < nE) {
    int d = dst[e], s = src[e];
    int pos = atomicAdd(&cursor[d], 1);
    float x = pd[d] + ps[s];
    x = x > 0.f ? x : 0.01f * x;
    ssx[pos] = make_int2(s, __float_as_int(x));
  }
}

// ---------------- per-node softmax + weighted aggregation ----------------
// one wave per destination node; lane handles feature pair (2*lane, 2*lane+1).
// Fast path (deg<=64): edge list held in registers, 8 gathers in flight.
__global__ __launch_bounds__(256) void aggregate_kernel(
    const int* __restrict__ offs, const int2* __restrict__ ssx,
    const unsigned* __restrict__ hv2, float* __restrict__ out, int nN) {
  int v = blockIdx.x * 4 + (threadIdx.x >> 6);
  if (v >= nN) return;
  int lane = threadIdx.x & 63;
  int s0 = offs[v], e1 = offs[v + 1];
  int deg = e1 - s0;
  float2* out2 = reinterpret_cast<float2*>(out) + (size_t)v * 64 + lane;
  if (deg == 0) {  // no incoming edges: c = 0 -> elu(0) = 0
    *out2 = make_float2(0.f, 0.f);
    return;
  }
  float acc0 = 0.f, acc1 = 0.f;
  if (deg <= 64) {
    // one edge per lane, everything else via shuffles
    int2 sx = ssx[s0 + (lane < deg ? lane : 0)];
    int se = sx.x;
    float xe = __int_as_float(sx.y);
    float m = lane < deg ? xe : -1e30f;
#pragma unroll
    for (int o = 32; o; o >>= 1) m = fmaxf(m, __shfl_xor(m, o));
    float ex = lane < deg ? __expf(xe - m) : 0.f;
    float ssum = ex;
#pragma unroll
    for (int o = 32; o; o >>= 1) ssum += __shfl_xor(ssum, o);
    float rinv = 1.f / ssum;  // ssum >= 1 (max element contributes exp(0))
    for (int i0 = 0; i0 < deg; i0 += 8) {
      int u[8];
#pragma unroll
      for (int j = 0; j < 8; ++j) {
        int jj = i0 + j;
        u[j] = __shfl(se, jj < deg ? jj : 0);
      }
      unsigned pk[8];
#pragma unroll
      for (int j = 0; j < 8; ++j) pk[j] = hv2[(u[j] << 6) + lane];  // 8 gathers in flight
      float aw[8];
#pragma unroll
      for (int j = 0; j < 8; ++j) {
        int jj = i0 + j;
        float exj = __shfl(ex, jj < deg ? jj : 0);
        aw[j] = jj < deg ? exj * rinv : 0.f;
      }
#pragma unroll
      for (int j = 0; j < 8; ++j) {
        acc0 += aw[j] * __uint_as_float(pk[j] << 16);
        acc1 += aw[j] * __uint_as_float(pk[j] & 0xffff0000u);
      }
    }
  } else {
    // rare fallback: 3-pass over global edge list
    float m = -1e30f;
    for (int i = s0 + lane; i < e1; i += 64) m = fmaxf(m, __int_as_float(ssx[i].y));
#pragma unroll
    for (int o = 32; o; o >>= 1) m = fmaxf(m, __shfl_xor(m, o));
    float ssum = 0.f;
    for (int i = s0 + lane; i < e1; i += 64) ssum += __expf(__int_as_float(ssx[i].y) - m);
#pragma unroll
    for (int o = 32; o; o >>= 1) ssum += __shfl_xor(ssum, o);
    float rinv = 1.f / ssum;
    for (int i0 = s0; i0 < e1; i0 += 8) {
      int u[8];
      float aw[8];
      unsigned pk[8];
#pragma unroll
      for (int j = 0; j < 8; ++j) {
        int idx = i0 + j;
        bool ok = idx < e1;
        int2 sx = ssx[ok ? idx : s0];
        u[j] = sx.x;
        aw[j] = ok ? __expf(__int_as_float(sx.y) - m) * rinv : 0.f;
      }
#pragma unroll
      for (int j = 0; j < 8; ++j) pk[j] = hv2[(u[j] << 6) + lane];
#pragma unroll
      for (int j = 0; j < 8; ++j) {
        acc0 += aw[j] * __uint_as_float(pk[j] << 16);
        acc1 += aw[j] * __uint_as_float(pk[j] & 0xffff0000u);
      }
    }
  }
  float e0 = acc0 > 0.f ? acc0 : expm1f(acc0);
  float e1v = acc1 > 0.f ? acc1 : expm1f(acc1);
  *out2 = make_float2(e0, e1v);
}

extern "C" void kernel_launch(void* const* d_in, const int* in_sizes, int n_in,
                              void* d_out, int out_size, void* d_ws, size_t ws_size,
                              hipStream_t stream) {
  const float* nf = (const float*)d_in[0];
  const int* src = (const int*)d_in[1];
  const int* dst = (const int*)d_in[2];
  const float* We = (const float*)d_in[3];
  const float* be = (const float*)d_in[4];
  const float* Wn = (const float*)d_in[5];
  const float* bn = (const float*)d_in[6];
  float* out = (float*)d_out;
  int nN = in_sizes[0] / 128;
  int nE = in_sizes[1];

  // workspace carve (~20 MB); keep 16B alignment for ssx/hv2/wsw
  char* wsp = (char*)d_ws;
  int2* ssx = (int2*)wsp;                      wsp += (size_t)nE * 8;
  unsigned* hv2 = (unsigned*)wsp;              wsp += (size_t)nN * 64 * 4;
  wsp = (char*)(((uintptr_t)wsp + 15) & ~(uintptr_t)15);
  ushort* wsw = (ushort*)wsp;                  wsp += 16384 * 2;
  float* pd = (float*)wsp;                     wsp += (size_t)nN * 4;
  float* ps = (float*)wsp;                     wsp += (size_t)nN * 4;
  int* deg = (int*)wsp;                        wsp += (size_t)nN * 4;
  int* offs = (int*)wsp;                       wsp += (size_t)(nN + 1) * 4;
  int* cursor = (int*)wsp;                     wsp += (size_t)nN * 4;
  int* bsum = (int*)wsp;                       wsp += 256 * 4;

  hipMemsetAsync(deg, 0, (size_t)nN * sizeof(int), stream);

  wconv_kernel<<<64, 256, 0, stream>>>(Wn, wsw);
  hv_mfma_kernel<<<(nN + 63) / 64, 256, 0, stream>>>(nf, wsw, bn, We, be, hv2, pd, ps, nN);
  count_kernel<<<(nE + 255) / 256, 256, 0, stream>>>(dst, deg, nE);
  int nB = (nN + 1023) / 1024;
  scan_blocksum<<<nB, 256, 0, stream>>>(deg, bsum, nN);
  scan_bsums<<<1, 64, 0, stream>>>(bsum, nB);
  scan_final<<<nB, 256, 0, stream>>>(deg, bsum, offs, cursor, nN);
  scatter_kernel<<<(nE + 255) / 256, 256, 0, stream>>>(src, dst, pd, ps, cursor, ssx, nE);
  aggregate_kernel<<<(nN + 3) / 4, 256, 0, stream>>>(offs, ssx, hv2, out, nN);
}

// Round 5
// 94.592 us; speedup vs baseline: 2.5924x; 1.6094x over previous
//
#include <hip/hip_runtime.h>
#include <hip/hip_bf16.h>
#include <math.h>

// Problem: N=50000 nodes, E=800000 edges, D=G=128.
// out[v,:] = elu( sum_{e: dst(e)=v} softmax_e(leaky(pd[dst]+ps[src]+b)) * hv[src(e),:] )
// pd[v] = nf[v]·W_edge[0:D] (+ b_edge), ps[v] = nf[v]·W_edge[D:2D]
// hv = leaky_relu(nf @ W_node + b_node) via bf16 MFMA, stored as packed bf16 pairs.
// Edge ordering via 2-level binned multisplit (64-dst buckets, fixed CAP slots);
// requires nN <= 65536 (src/dst packed in 16 bits) — holds for this problem.

#define BK_SHIFT 6
#define BK_CAP 2048
#define BIN_CHUNK 4096

using bf16x8 = __attribute__((ext_vector_type(8))) __bf16;
using f32x4 = __attribute__((ext_vector_type(4))) float;

static __device__ __forceinline__ unsigned pack_bf16(float x0, float x1) {
  unsigned u0 = (unsigned)__bfloat16_as_ushort(__float2bfloat16(x0));
  unsigned u1 = (unsigned)__bfloat16_as_ushort(__float2bfloat16(x1));
  return u0 | (u1 << 16);
}

// ---- one-time: convert Wn (128x128 f32) to bf16, pre-swizzled into B-fragment order ----
__global__ void wconv_kernel(const float* __restrict__ Wn, ushort* __restrict__ wsw) {
  int i = blockIdx.x * 256 + threadIdx.x;  // 0..16383
  int j = i & 7, l = (i >> 3) & 63, ct = (i >> 9) & 7, kstep = i >> 12;
  int k = kstep * 32 + ((l >> 4) << 3) + j;
  int c = ct * 16 + (l & 15);
  wsw[i] = __bfloat16_as_ushort(__float2bfloat16(Wn[k * 128 + c]));
}

// ---------------- fused: hv MFMA GEMM (bf16) + per-node edge scalars ----------------
__global__ __launch_bounds__(256) void hv_mfma_kernel(
    const float* __restrict__ nf, const ushort* __restrict__ wsw,
    const float* __restrict__ bn, const float* __restrict__ We,
    const float* __restrict__ be, unsigned* __restrict__ hv2,
    float* __restrict__ pd, float* __restrict__ ps, int nN) {
  __shared__ unsigned Atile[64 * 64];  // 64 rows x 256B of bf16, XOR-swizzled 16B slots
  int row0 = blockIdx.x * 64;
  int t = threadIdx.x;
#pragma unroll
  for (int ss = 0; ss < 4; ++ss) {
    int s = t + ss * 256;
    int r = s >> 4, sl = s & 15;
    int gr = row0 + r;
    float4 f0 = make_float4(0.f, 0.f, 0.f, 0.f), f1 = f0;
    if (gr < nN) {
      const float4* p = reinterpret_cast<const float4*>(nf + (size_t)gr * 128 + sl * 8);
      f0 = p[0];
      f1 = p[1];
    }
    uint4 pk;
    pk.x = pack_bf16(f0.x, f0.y);
    pk.y = pack_bf16(f0.z, f0.w);
    pk.z = pack_bf16(f1.x, f1.y);
    pk.w = pack_bf16(f1.z, f1.w);
    int byte = r * 256 + ((sl * 16) ^ ((r & 7) << 4));  // T2 swizzle vs 16-way conflict
    *reinterpret_cast<uint4*>(reinterpret_cast<char*>(Atile) + byte) = pk;
  }
  __syncthreads();
  int lane = t & 63, w = t >> 6;
  // edge-projection scalars (fp32, reads nf from global -> L1/L2-hot after staging)
  float we0 = We[lane], we1 = We[64 + lane], we2 = We[128 + lane], we3 = We[192 + lane];
  float bev = be[0];
  for (int rr = 0; rr < 16; ++rr) {
    int gr = row0 + w * 16 + rr;
    if (gr >= nN) break;  // wave-uniform
    const float* rowp = nf + (size_t)gr * 128;
    float a0 = rowp[lane], a1 = rowp[64 + lane];
    float pdv = a0 * we0 + a1 * we1;
    float psv = a0 * we2 + a1 * we3;
#pragma unroll
    for (int o = 32; o; o >>= 1) {
      pdv += __shfl_xor(pdv, o);
      psv += __shfl_xor(psv, o);
    }
    if (lane == 0) {
      pd[gr] = pdv + bev;  // bias folded (added once per edge)
      ps[gr] = psv;
    }
  }
  // MFMA: wave w owns rows w*16..w*16+15, 8 col-tiles of 16, K=128 (4 ksteps)
  f32x4 acc[8];
#pragma unroll
  for (int c = 0; c < 8; ++c) acc[c] = (f32x4){0.f, 0.f, 0.f, 0.f};
  int rl = w * 16 + (lane & 15);
  const char* abase = reinterpret_cast<const char*>(Atile) + rl * 256;
  int ksel = (lane >> 4) * 16;
#pragma unroll
  for (int kstep = 0; kstep < 4; ++kstep) {
    int kb = kstep * 64 + ksel;
    bf16x8 afrag = *reinterpret_cast<const bf16x8*>(abase + (kb ^ ((rl & 7) << 4)));
#pragma unroll
    for (int ct = 0; ct < 8; ++ct) {
      bf16x8 bfrag = *reinterpret_cast<const bf16x8*>(wsw + ((size_t)((kstep * 8 + ct) * 64 + lane)) * 8);
      acc[ct] = __builtin_amdgcn_mfma_f32_16x16x32_bf16(afrag, bfrag, acc[ct], 0, 0, 0);
    }
  }
  // epilogue: D layout col=lane&15, row=(lane>>4)*4+reg; pack (c, c+1) via shfl
  int colbase = lane & 15;
  int rbase = row0 + w * 16 + ((lane >> 4) << 2);
#pragma unroll
  for (int ct = 0; ct < 8; ++ct) {
    int col = ct * 16 + colbase;
    float bb = bn[col];
#pragma unroll
    for (int r = 0; r < 4; ++r) {
      float x = acc[ct][r] + bb;
      x = x > 0.f ? x : 0.01f * x;
      float y = __shfl_xor(x, 1);
      int gr = rbase + r;
      if (!(lane & 1) && gr < nN)
        hv2[(size_t)gr * 64 + ct * 8 + (colbase >> 1)] = pack_bf16(x, y);
    }
  }
}

// ---------------- phase 1: multisplit bin by dst>>6 into fixed-CAP slots ----------------
__global__ __launch_bounds__(256) void bin_kernel(
    const int* __restrict__ src, const int* __restrict__ dst,
    int* __restrict__ bcnt, unsigned* __restrict__ inter, int nE, int nB) {
  __shared__ int cnt[1024];  // supports nN <= 65536
  int t = threadIdx.x;
  for (int b = t; b < nB; b += 256) cnt[b] = 0;
  __syncthreads();
  int base = blockIdx.x * BIN_CHUNK;
  int dv[16];
#pragma unroll
  for (int k = 0; k < 16; ++k) {
    int e = base + t + k * 256;
    dv[k] = (e < nE) ? dst[e] : -1;
    if (dv[k] >= 0) atomicAdd(&cnt[dv[k] >> BK_SHIFT], 1);
  }
  __syncthreads();
  // reserve global bucket ranges; counter slot becomes this wg's running base
  for (int b = t; b < nB; b += 256) {
    int c = cnt[b];
    cnt[b] = c ? atomicAdd(&bcnt[b], c) : 0;
  }
  __syncthreads();
#pragma unroll
  for (int k = 0; k < 16; ++k) {
    int e = base + t + k * 256;
    if (e < nE) {
      int d = dv[k];
      int b = d >> BK_SHIFT;
      int pos = atomicAdd(&cnt[b], 1);
      if (pos < BK_CAP)
        inter[(size_t)b * BK_CAP + pos] = ((unsigned)src[e] << BK_SHIFT) | (unsigned)(d & 63);
    }
  }
}

// ---------------- phase 2: per-bucket LDS sort -> ssorted + offs/deg ----------------
__global__ __launch_bounds__(256) void place_kernel(
    const int* __restrict__ bcnt, const unsigned* __restrict__ inter,
    ushort* __restrict__ ssorted, int* __restrict__ offs, int* __restrict__ degv, int nN) {
  __shared__ unsigned recs[BK_CAP];
  __shared__ ushort stage[BK_CAP];
  __shared__ int cnt[64], cur[64];
  int b = blockIdx.x;
  int t = threadIdx.x;
  int cntE = min(bcnt[b], BK_CAP);
  for (int i = t; i < cntE; i += 256) recs[i] = inter[(size_t)b * BK_CAP + i];
  if (t < 64) cnt[t] = 0;
  __syncthreads();
  for (int i = t; i < cntE; i += 256) atomicAdd(&cnt[recs[i] & 63], 1);
  __syncthreads();
  if (t < 64) {  // wave-0 exclusive scan of the 64 per-dst counts
    int c = cnt[t];
    int incl = c;
#pragma unroll
    for (int o = 1; o < 64; o <<= 1) {
      int x = __shfl_up(incl, o);
      if (t >= o) incl += x;
    }
    int excl = incl - c;
    cur[t] = excl;
    int node = b * 64 + t;
    if (node < nN) {
      offs[node] = b * BK_CAP + excl;
      degv[node] = c;
    }
  }
  __syncthreads();
  for (int i = t; i < cntE; i += 256) {
    unsigned r = recs[i];
    int pos = atomicAdd(&cur[r & 63], 1);
    stage[pos] = (ushort)(r >> BK_SHIFT);
  }
  __syncthreads();
  for (int i = t; i < cntE; i += 256) ssorted[(size_t)b * BK_CAP + i] = stage[i];
}

// ---------------- per-node softmax + weighted aggregation ----------------
// one wave per destination node; lane handles feature pair (2*lane, 2*lane+1).
__global__ __launch_bounds__(256) void aggregate_kernel(
    const int* __restrict__ offs, const int* __restrict__ degv,
    const ushort* __restrict__ ssorted, const float* __restrict__ pd,
    const float* __restrict__ ps, const unsigned* __restrict__ hv2,
    float* __restrict__ out, int nN) {
  int v = blockIdx.x * 4 + (threadIdx.x >> 6);
  if (v >= nN) return;
  int lane = threadIdx.x & 63;
  int s0 = offs[v];
  int deg = degv[v];
  float2* out2 = reinterpret_cast<float2*>(out) + (size_t)v * 64 + lane;
  if (deg == 0) {  // no incoming edges: c = 0 -> elu(0) = 0
    *out2 = make_float2(0.f, 0.f);
    return;
  }
  float pdv = pd[v];
  float acc0 = 0.f, acc1 = 0.f;
  if (deg <= 64) {
    // one edge per lane; logit recomputed from L2-resident ps
    int se = ssorted[s0 + (lane < deg ? lane : 0)];
    float xe = pdv + ps[se];
    xe = xe > 0.f ? xe : 0.01f * xe;
    float m = lane < deg ? xe : -1e30f;
#pragma unroll
    for (int o = 32; o; o >>= 1) m = fmaxf(m, __shfl_xor(m, o));
    float ex = lane < deg ? __expf(xe - m) : 0.f;
    float ssum = ex;
#pragma unroll
    for (int o = 32; o; o >>= 1) ssum += __shfl_xor(ssum, o);
    float rinv = 1.f / ssum;  // ssum >= 1 (max element contributes exp(0))
    for (int i0 = 0; i0 < deg; i0 += 8) {
      int u[8];
#pragma unroll
      for (int j = 0; j < 8; ++j) {
        int jj = i0 + j;
        u[j] = __shfl(se, jj < deg ? jj : 0);
      }
      unsigned pk[8];
#pragma unroll
      for (int j = 0; j < 8; ++j) pk[j] = hv2[(u[j] << 6) + lane];  // 8 gathers in flight
      float aw[8];
#pragma unroll
      for (int j = 0; j < 8; ++j) {
        int jj = i0 + j;
        float exj = __shfl(ex, jj < deg ? jj : 0);
        aw[j] = jj < deg ? exj * rinv : 0.f;
      }
#pragma unroll
      for (int j = 0; j < 8; ++j) {
        acc0 += aw[j] * __uint_as_float(pk[j] << 16);
        acc1 += aw[j] * __uint_as_float(pk[j] & 0xffff0000u);
      }
    }
  } else {
    // rare fallback: 3-pass over global edge list
    float m = -1e30f;
    for (int i = s0 + lane; i < s0 + deg; i += 64) {
      float x = pdv + ps[ssorted[i]];
      x = x > 0.f ? x : 0.01f * x;
      m = fmaxf(m, x);
    }
#pragma unroll
    for (int o = 32; o; o >>= 1) m = fmaxf(m, __shfl_xor(m, o));
    float ssum = 0.f;
    for (int i = s0 + lane; i < s0 + deg; i += 64) {
      float x = pdv + ps[ssorted[i]];
      x = x > 0.f ? x : 0.01f * x;
      ssum += __expf(x - m);
    }
#pragma unroll
    for (int o = 32; o; o >>= 1) ssum += __shfl_xor(ssum, o);
    float rinv = 1.f / ssum;
    for (int i0 = s0; i0 < s0 + deg; i0 += 8) {
      int u[8];
      float aw[8];
      unsigned pk[8];
#pragma unroll
      for (int j = 0; j < 8; ++j) {
        int idx = i0 + j;
        bool ok = idx < s0 + deg;
        int s = ssorted[ok ? idx : s0];
        u[j] = s;
        float x = pdv + ps[s];
        x = x > 0.f ? x : 0.01f * x;
        aw[j] = ok ? __expf(x - m) * rinv : 0.f;
      }
#pragma unroll
      for (int j = 0; j < 8; ++j) pk[j] = hv2[(u[j] << 6) + lane];
#pragma unroll
      for (int j = 0; j < 8; ++j) {
        acc0 += aw[j] * __uint_as_float(pk[j] << 16);
        acc1 += aw[j] * __uint_as_float(pk[j] & 0xffff0000u);
      }
    }
  }
  float e0 = acc0 > 0.f ? acc0 : expm1f(acc0);
  float e1v = acc1 > 0.f ? acc1 : expm1f(acc1);
  *out2 = make_float2(e0, e1v);
}

extern "C" void kernel_launch(void* const* d_in, const int* in_sizes, int n_in,
                              void* d_out, int out_size, void* d_ws, size_t ws_size,
                              hipStream_t stream) {
  const float* nf = (const float*)d_in[0];
  const int* src = (const int*)d_in[1];
  const int* dst = (const int*)d_in[2];
  const float* We = (const float*)d_in[3];
  const float* be = (const float*)d_in[4];
  const float* Wn = (const float*)d_in[5];
  const float* bn = (const float*)d_in[6];
  float* out = (float*)d_out;
  int nN = in_sizes[0] / 128;
  int nE = in_sizes[1];
  int nB = (nN + 63) >> BK_SHIFT;

  // workspace carve (~23 MB), 16B-aligned chunks first
  char* wsp = (char*)d_ws;
  unsigned* hv2 = (unsigned*)wsp;   wsp += (size_t)nN * 64 * 4;
  unsigned* inter = (unsigned*)wsp; wsp += (size_t)nB * BK_CAP * 4;
  ushort* wsw = (ushort*)wsp;       wsp += 16384 * 2;
  float* pd = (float*)wsp;          wsp += (size_t)nN * 4;
  float* ps = (float*)wsp;          wsp += (size_t)nN * 4;
  int* offs = (int*)wsp;            wsp += (size_t)nN * 4;
  int* degv = (int*)wsp;            wsp += (size_t)nN * 4;
  int* bcnt = (int*)wsp;            wsp += (size_t)nB * 4;
  ushort* ssorted = (ushort*)wsp;   wsp += (size_t)nB * BK_CAP * 2;

  hipMemsetAsync(bcnt, 0, (size_t)nB * sizeof(int), stream);

  wconv_kernel<<<64, 256, 0, stream>>>(Wn, wsw);
  hv_mfma_kernel<<<(nN + 63) / 64, 256, 0, stream>>>(nf, wsw, bn, We, be, hv2, pd, ps, nN);
  bin_kernel<<<(nE + BIN_CHUNK - 1) / BIN_CHUNK, 256, 0, stream>>>(src, dst, bcnt, inter, nE, nB);
  place_kernel<<<nB, 256, 0, stream>>>(bcnt, inter, ssorted, offs, degv, nN);
  aggregate_kernel<<<(nN + 3) / 4, 256, 0, stream>>>(offs, degv, ssorted, pd, ps, hv2, out, nN);
}

// Round 6
// 89.730 us; speedup vs baseline: 2.7329x; 1.0542x over previous
//
#include <hip/hip_runtime.h>
#include <hip/hip_bf16.h>
#include <math.h>

// Problem: N=50000 nodes, E=800000 edges, D=G=128.
// out[v,:] = elu( sum_{e: dst(e)=v} softmax_e(leaky(pd[dst]+ps[src]+b)) * hv[src(e),:] )
// pd[v] = nf[v]·W_edge[0:D] (+ b_edge), ps[v] = nf[v]·W_edge[D:2D]
// hv = leaky_relu(nf @ W_node + b_node) via bf16 MFMA, stored as packed bf16 pairs.
// Edge ordering via 2-level binned multisplit (64-dst buckets, fixed CAP slots);
// requires nN <= 65536 (src/dst packed in 16 bits) — holds for this problem.

#define BK_SHIFT 6
#define BK_CAP 2048
#define BIN_CHUNK 4096

using bf16x8 = __attribute__((ext_vector_type(8))) __bf16;
using f32x4 = __attribute__((ext_vector_type(4))) float;

static __device__ __forceinline__ unsigned pack_bf16(float x0, float x1) {
  unsigned u0 = (unsigned)__bfloat16_as_ushort(__float2bfloat16(x0));
  unsigned u1 = (unsigned)__bfloat16_as_ushort(__float2bfloat16(x1));
  return u0 | (u1 << 16);
}

// ---- one-time: convert Wn (128x128 f32) to bf16, pre-swizzled into B-fragment order.
// Also zeroes bcnt (replaces a hipMemsetAsync whose fill kernel cost ~42 us in-graph).
__global__ void wconv_kernel(const float* __restrict__ Wn, ushort* __restrict__ wsw,
                             int* __restrict__ bcnt, int nB) {
  int i = blockIdx.x * 256 + threadIdx.x;  // 0..16383
  if (i < nB) bcnt[i] = 0;
  int j = i & 7, l = (i >> 3) & 63, ct = (i >> 9) & 7, kstep = i >> 12;
  int k = kstep * 32 + ((l >> 4) << 3) + j;
  int c = ct * 16 + (l & 15);
  wsw[i] = __bfloat16_as_ushort(__float2bfloat16(Wn[k * 128 + c]));
}

// ---------------- fused: hv MFMA GEMM (bf16) + per-node edge scalars ----------------
__global__ __launch_bounds__(256) void hv_mfma_kernel(
    const float* __restrict__ nf, const ushort* __restrict__ wsw,
    const float* __restrict__ bn, const float* __restrict__ We,
    const float* __restrict__ be, unsigned* __restrict__ hv2,
    float* __restrict__ pd, float* __restrict__ ps, int nN) {
  __shared__ unsigned Atile[64 * 64];  // 64 rows x 256B of bf16, XOR-swizzled 16B slots
  int row0 = blockIdx.x * 64;
  int t = threadIdx.x;
#pragma unroll
  for (int ss = 0; ss < 4; ++ss) {
    int s = t + ss * 256;
    int r = s >> 4, sl = s & 15;
    int gr = row0 + r;
    float4 f0 = make_float4(0.f, 0.f, 0.f, 0.f), f1 = f0;
    if (gr < nN) {
      const float4* p = reinterpret_cast<const float4*>(nf + (size_t)gr * 128 + sl * 8);
      f0 = p[0];
      f1 = p[1];
    }
    uint4 pk;
    pk.x = pack_bf16(f0.x, f0.y);
    pk.y = pack_bf16(f0.z, f0.w);
    pk.z = pack_bf16(f1.x, f1.y);
    pk.w = pack_bf16(f1.z, f1.w);
    int byte = r * 256 + ((sl * 16) ^ ((r & 7) << 4));  // T2 swizzle vs 16-way conflict
    *reinterpret_cast<uint4*>(reinterpret_cast<char*>(Atile) + byte) = pk;
  }
  __syncthreads();
  int lane = t & 63, w = t >> 6;
  // edge-projection scalars (fp32, reads nf from global -> L1/L2-hot after staging)
  float we0 = We[lane], we1 = We[64 + lane], we2 = We[128 + lane], we3 = We[192 + lane];
  float bev = be[0];
  for (int rr = 0; rr < 16; ++rr) {
    int gr = row0 + w * 16 + rr;
    if (gr >= nN) break;  // wave-uniform
    const float* rowp = nf + (size_t)gr * 128;
    float a0 = rowp[lane], a1 = rowp[64 + lane];
    float pdv = a0 * we0 + a1 * we1;
    float psv = a0 * we2 + a1 * we3;
#pragma unroll
    for (int o = 32; o; o >>= 1) {
      pdv += __shfl_xor(pdv, o);
      psv += __shfl_xor(psv, o);
    }
    if (lane == 0) {
      pd[gr] = pdv + bev;  // bias folded (added once per edge)
      ps[gr] = psv;
    }
  }
  // MFMA: wave w owns rows w*16..w*16+15, 8 col-tiles of 16, K=128 (4 ksteps)
  f32x4 acc[8];
#pragma unroll
  for (int c = 0; c < 8; ++c) acc[c] = (f32x4){0.f, 0.f, 0.f, 0.f};
  int rl = w * 16 + (lane & 15);
  const char* abase = reinterpret_cast<const char*>(Atile) + rl * 256;
  int ksel = (lane >> 4) * 16;
#pragma unroll
  for (int kstep = 0; kstep < 4; ++kstep) {
    int kb = kstep * 64 + ksel;
    bf16x8 afrag = *reinterpret_cast<const bf16x8*>(abase + (kb ^ ((rl & 7) << 4)));
#pragma unroll
    for (int ct = 0; ct < 8; ++ct) {
      bf16x8 bfrag = *reinterpret_cast<const bf16x8*>(wsw + ((size_t)((kstep * 8 + ct) * 64 + lane)) * 8);
      acc[ct] = __builtin_amdgcn_mfma_f32_16x16x32_bf16(afrag, bfrag, acc[ct], 0, 0, 0);
    }
  }
  // epilogue: D layout col=lane&15, row=(lane>>4)*4+reg; pack (c, c+1) via shfl
  int colbase = lane & 15;
  int rbase = row0 + w * 16 + ((lane >> 4) << 2);
#pragma unroll
  for (int ct = 0; ct < 8; ++ct) {
    int col = ct * 16 + colbase;
    float bb = bn[col];
#pragma unroll
    for (int r = 0; r < 4; ++r) {
      float x = acc[ct][r] + bb;
      x = x > 0.f ? x : 0.01f * x;
      float y = __shfl_xor(x, 1);
      int gr = rbase + r;
      if (!(lane & 1) && gr < nN)
        hv2[(size_t)gr * 64 + ct * 8 + (colbase >> 1)] = pack_bf16(x, y);
    }
  }
}

// ---------------- phase 1: multisplit bin by dst>>6 into fixed-CAP slots ----------------
__global__ __launch_bounds__(256) void bin_kernel(
    const int* __restrict__ src, const int* __restrict__ dst,
    int* __restrict__ bcnt, unsigned* __restrict__ inter, int nE, int nB) {
  __shared__ int cnt[1024];  // supports nN <= 65536
  int t = threadIdx.x;
  for (int b = t; b < nB; b += 256) cnt[b] = 0;
  __syncthreads();
  int base = blockIdx.x * BIN_CHUNK;
  int dv[16];
#pragma unroll
  for (int k = 0; k < 16; ++k) {
    int e = base + t + k * 256;
    dv[k] = (e < nE) ? dst[e] : -1;
    if (dv[k] >= 0) atomicAdd(&cnt[dv[k] >> BK_SHIFT], 1);
  }
  __syncthreads();
  // reserve global bucket ranges; counter slot becomes this wg's running base
  for (int b = t; b < nB; b += 256) {
    int c = cnt[b];
    cnt[b] = c ? atomicAdd(&bcnt[b], c) : 0;
  }
  __syncthreads();
#pragma unroll
  for (int k = 0; k < 16; ++k) {
    int e = base + t + k * 256;
    if (e < nE) {
      int d = dv[k];
      int b = d >> BK_SHIFT;
      int pos = atomicAdd(&cnt[b], 1);
      if (pos < BK_CAP)
        inter[(size_t)b * BK_CAP + pos] = ((unsigned)src[e] << BK_SHIFT) | (unsigned)(d & 63);
    }
  }
}

// ---------------- phase 2: per-bucket LDS sort -> ssorted + offs/deg ----------------
__global__ __launch_bounds__(256) void place_kernel(
    const int* __restrict__ bcnt, const unsigned* __restrict__ inter,
    ushort* __restrict__ ssorted, int* __restrict__ offs, int* __restrict__ degv, int nN) {
  __shared__ unsigned recs[BK_CAP];
  __shared__ ushort stage[BK_CAP];
  __shared__ int cnt[64], cur[64];
  int b = blockIdx.x;
  int t = threadIdx.x;
  int cntE = min(bcnt[b], BK_CAP);
  for (int i = t; i < cntE; i += 256) recs[i] = inter[(size_t)b * BK_CAP + i];
  if (t < 64) cnt[t] = 0;
  __syncthreads();
  for (int i = t; i < cntE; i += 256) atomicAdd(&cnt[recs[i] & 63], 1);
  __syncthreads();
  if (t < 64) {  // wave-0 exclusive scan of the 64 per-dst counts
    int c = cnt[t];
    int incl = c;
#pragma unroll
    for (int o = 1; o < 64; o <<= 1) {
      int x = __shfl_up(incl, o);
      if (t >= o) incl += x;
    }
    int excl = incl - c;
    cur[t] = excl;
    int node = b * 64 + t;
    if (node < nN) {
      offs[node] = b * BK_CAP + excl;
      degv[node] = c;
    }
  }
  __syncthreads();
  for (int i = t; i < cntE; i += 256) {
    unsigned r = recs[i];
    int pos = atomicAdd(&cur[r & 63], 1);
    stage[pos] = (ushort)(r >> BK_SHIFT);
  }
  __syncthreads();
  for (int i = t; i < cntE; i += 256) ssorted[(size_t)b * BK_CAP + i] = stage[i];
}

// ---------------- per-node softmax + weighted aggregation ----------------
// one wave per destination node; lane handles feature pair (2*lane, 2*lane+1).
__global__ __launch_bounds__(256) void aggregate_kernel(
    const int* __restrict__ offs, const int* __restrict__ degv,
    const ushort* __restrict__ ssorted, const float* __restrict__ pd,
    const float* __restrict__ ps, const unsigned* __restrict__ hv2,
    float* __restrict__ out, int nN) {
  int v = blockIdx.x * 4 + (threadIdx.x >> 6);
  if (v >= nN) return;
  int lane = threadIdx.x & 63;
  int s0 = offs[v];
  int deg = degv[v];
  float2* out2 = reinterpret_cast<float2*>(out) + (size_t)v * 64 + lane;
  if (deg == 0) {  // no incoming edges: c = 0 -> elu(0) = 0
    *out2 = make_float2(0.f, 0.f);
    return;
  }
  float pdv = pd[v];
  float acc0 = 0.f, acc1 = 0.f;
  if (deg <= 64) {
    // one edge per lane; logit recomputed from L2-resident ps
    int se = ssorted[s0 + (lane < deg ? lane : 0)];
    float xe = pdv + ps[se];
    xe = xe > 0.f ? xe : 0.01f * xe;
    float m = lane < deg ? xe : -1e30f;
#pragma unroll
    for (int o = 32; o; o >>= 1) m = fmaxf(m, __shfl_xor(m, o));
    float ex = lane < deg ? __expf(xe - m) : 0.f;
    float ssum = ex;
#pragma unroll
    for (int o = 32; o; o >>= 1) ssum += __shfl_xor(ssum, o);
    float rinv = 1.f / ssum;  // ssum >= 1 (max element contributes exp(0))
    for (int i0 = 0; i0 < deg; i0 += 8) {
      int u[8];
#pragma unroll
      for (int j = 0; j < 8; ++j) {
        int jj = i0 + j;
        u[j] = __shfl(se, jj < deg ? jj : 0);
      }
      unsigned pk[8];
#pragma unroll
      for (int j = 0; j < 8; ++j) pk[j] = hv2[(u[j] << 6) + lane];  // 8 gathers in flight
      float aw[8];
#pragma unroll
      for (int j = 0; j < 8; ++j) {
        int jj = i0 + j;
        float exj = __shfl(ex, jj < deg ? jj : 0);
        aw[j] = jj < deg ? exj * rinv : 0.f;
      }
#pragma unroll
      for (int j = 0; j < 8; ++j) {
        acc0 += aw[j] * __uint_as_float(pk[j] << 16);
        acc1 += aw[j] * __uint_as_float(pk[j] & 0xffff0000u);
      }
    }
  } else {
    // rare fallback: 3-pass over global edge list
    float m = -1e30f;
    for (int i = s0 + lane; i < s0 + deg; i += 64) {
      float x = pdv + ps[ssorted[i]];
      x = x > 0.f ? x : 0.01f * x;
      m = fmaxf(m, x);
    }
#pragma unroll
    for (int o = 32; o; o >>= 1) m = fmaxf(m, __shfl_xor(m, o));
    float ssum = 0.f;
    for (int i = s0 + lane; i < s0 + deg; i += 64) {
      float x = pdv + ps[ssorted[i]];
      x = x > 0.f ? x : 0.01f * x;
      ssum += __expf(x - m);
    }
#pragma unroll
    for (int o = 32; o; o >>= 1) ssum += __shfl_xor(ssum, o);
    float rinv = 1.f / ssum;
    for (int i0 = s0; i0 < s0 + deg; i0 += 8) {
      int u[8];
      float aw[8];
      unsigned pk[8];
#pragma unroll
      for (int j = 0; j < 8; ++j) {
        int idx = i0 + j;
        bool ok = idx < s0 + deg;
        int s = ssorted[ok ? idx : s0];
        u[j] = s;
        float x = pdv + ps[s];
        x = x > 0.f ? x : 0.01f * x;
        aw[j] = ok ? __expf(x - m) * rinv : 0.f;
      }
#pragma unroll
      for (int j = 0; j < 8; ++j) pk[j] = hv2[(u[j] << 6) + lane];
#pragma unroll
      for (int j = 0; j < 8; ++j) {
        acc0 += aw[j] * __uint_as_float(pk[j] << 16);
        acc1 += aw[j] * __uint_as_float(pk[j] & 0xffff0000u);
      }
    }
  }
  float e0 = acc0 > 0.f ? acc0 : expm1f(acc0);
  float e1v = acc1 > 0.f ? acc1 : expm1f(acc1);
  *out2 = make_float2(e0, e1v);
}

extern "C" void kernel_launch(void* const* d_in, const int* in_sizes, int n_in,
                              void* d_out, int out_size, void* d_ws, size_t ws_size,
                              hipStream_t stream) {
  const float* nf = (const float*)d_in[0];
  const int* src = (const int*)d_in[1];
  const int* dst = (const int*)d_in[2];
  const float* We = (const float*)d_in[3];
  const float* be = (const float*)d_in[4];
  const float* Wn = (const float*)d_in[5];
  const float* bn = (const float*)d_in[6];
  float* out = (float*)d_out;
  int nN = in_sizes[0] / 128;
  int nE = in_sizes[1];
  int nB = (nN + 63) >> BK_SHIFT;

  // workspace carve (~23 MB), 16B-aligned chunks first
  char* wsp = (char*)d_ws;
  unsigned* hv2 = (unsigned*)wsp;   wsp += (size_t)nN * 64 * 4;
  unsigned* inter = (unsigned*)wsp; wsp += (size_t)nB * BK_CAP * 4;
  ushort* wsw = (ushort*)wsp;       wsp += 16384 * 2;
  float* pd = (float*)wsp;          wsp += (size_t)nN * 4;
  float* ps = (float*)wsp;          wsp += (size_t)nN * 4;
  int* offs = (int*)wsp;            wsp += (size_t)nN * 4;
  int* degv = (int*)wsp;            wsp += (size_t)nN * 4;
  int* bcnt = (int*)wsp;            wsp += (size_t)nB * 4;
  ushort* ssorted = (ushort*)wsp;   wsp += (size_t)nB * BK_CAP * 2;

  // wconv also zeroes bcnt (stream-ordered before bin_kernel) — replaces a
  // hipMemsetAsync whose fill kernel cost ~42 us inside the captured graph.
  wconv_kernel<<<64, 256, 0, stream>>>(Wn, wsw, bcnt, nB);
  hv_mfma_kernel<<<(nN + 63) / 64, 256, 0, stream>>>(nf, wsw, bn, We, be, hv2, pd, ps, nN);
  bin_kernel<<<(nE + BIN_CHUNK - 1) / BIN_CHUNK, 256, 0, stream>>>(src, dst, bcnt, inter, nE, nB);
  place_kernel<<<nB, 256, 0, stream>>>(bcnt, inter, ssorted, offs, degv, nN);
  aggregate_kernel<<<(nN + 3) / 4, 256, 0, stream>>>(offs, degv, ssorted, pd, ps, hv2, out, nN);
}